// Round 10
// baseline (42415.128 us; speedup 1.0000x reference)
//
#include <hip/hip_runtime.h>

// ---------------------------------------------------------------- encoder
// One block per token (all 8 batches in one launch); shared zin/hid. f32.
__global__ __launch_bounds__(256) void encoder_kernel(
    const float* __restrict__ xc, const float* __restrict__ yc, const float* __restrict__ xt,
    const float* __restrict__ W1, const float* __restrict__ b1,
    const float* __restrict__ W2, const float* __restrict__ b2,
    float* __restrict__ z)
{
  __shared__ float zin[10];
  __shared__ float hid[256];
  int blk = blockIdx.x; int b = blk>>10; int t = blk & 1023;
  int tid = threadIdx.x;
  if (tid < 10){
    float v;
    if (tid < 8)      v = (t<512) ? xc[((size_t)b*512+t)*8+tid] : xt[((size_t)b*512+(t-512))*8+tid];
    else if (tid==8)  v = (t<512) ? yc[(size_t)b*512+t] : 0.f;
    else              v = (t<512) ? 0.f : 1.f;
    zin[tid]=v;
  }
  __syncthreads();
  float s = b1[tid];
  #pragma unroll
  for (int i=0;i<10;i++) s += zin[i]*W1[i*256+tid];
  hid[tid] = fmaxf(s, 0.f);
  __syncthreads();
  float o = b2[tid];
  for (int j=0;j<256;j++) o += hid[j]*W2[j*256+tid];
  z[((size_t)b*1024+t)*256 + tid] = o;
}

// ---------------------------------------------------------------- layernorm
__global__ __launch_bounds__(64) void ln_naive(
    const float* __restrict__ z, const float* __restrict__ g,
    const float* __restrict__ be, float* __restrict__ h, int rows)
{
  int row = blockIdx.x*64 + threadIdx.x;
  if (row >= rows) return;
  const float* x = z + (size_t)row*256;
  float mu = 0.f;
  for (int i=0;i<256;i++) mu += x[i];
  mu *= (1.f/256.f);
  float var = 0.f;
  for (int i=0;i<256;i++){ float d = x[i]-mu; var += d*d; }
  var *= (1.f/256.f);
  float r = rsqrtf(var + 1e-5f);
  float* y = h + (size_t)row*256;
  for (int i=0;i<256;i++) y[i] = (x[i]-mu)*r*g[i] + be[i];
}

// ---------------------------------------------------------------- naive GEMM
// out[row][col] = (relu?)(bias[col] + sum_k A[row][k]*B[k][col]) (+ resid)
__global__ __launch_bounds__(256) void gemm_naive(
    const float* __restrict__ A, const float* __restrict__ B,
    const float* __restrict__ bias, const float* __restrict__ resid,
    float* __restrict__ out, int relu_flag, int M, int N, int K)
{
  int idx = blockIdx.x*256 + threadIdx.x;
  if (idx >= M*N) return;
  int row = idx / N, col = idx - row*N;
  float s = bias[col];
  for (int k=0;k<K;k++) s += A[(size_t)row*K + k] * B[(size_t)k*N + col];
  if (relu_flag) s = fmaxf(s, 0.f);
  if (resid) s += resid[idx];
  out[idx] = s;
}

// ---------------------------------------------------------------- naive attention
// One thread per (h,q), one batch. qkv: [1024][768] f32 (q|k|v, 8 heads x 32).
// Keys 0..511 for all rows; target rows (q>=512) also attend to themselves.
__global__ __launch_bounds__(64) void attn_naive(
    const float* __restrict__ qkv, float* __restrict__ o)
{
  int idx = blockIdx.x*64 + threadIdx.x;   // 8192 threads
  if (idx >= 8192) return;
  int h = idx >> 10;
  int q = idx & 1023;
  const float sc = 0.17677669529663687f;   // 1/sqrt(32)
  const float* Q = qkv + (size_t)q*768 + h*32;
  int nk = (q >= 512) ? 513 : 512;
  float mx = -1e30f;
  for (int j=0;j<nk;j++){
    int kr = (j<512) ? j : q;
    const float* Kp = qkv + (size_t)kr*768 + 256 + h*32;
    float dot = 0.f;
    #pragma unroll
    for (int d=0;d<32;d++) dot += Q[d]*Kp[d];
    dot *= sc;
    mx = fmaxf(mx, dot);
  }
  float acc[32];
  #pragma unroll
  for (int d=0;d<32;d++) acc[d]=0.f;
  float lsum = 0.f;
  for (int j=0;j<nk;j++){
    int kr = (j<512) ? j : q;
    const float* Kp = qkv + (size_t)kr*768 + 256 + h*32;
    float dot = 0.f;
    #pragma unroll
    for (int d=0;d<32;d++) dot += Q[d]*Kp[d];
    dot *= sc;
    float p = __expf(dot - mx);
    lsum += p;
    const float* Vp = qkv + (size_t)kr*768 + 512 + h*32;
    #pragma unroll
    for (int d=0;d<32;d++) acc[d] += p*Vp[d];
  }
  float inv = 1.f/lsum;
  #pragma unroll
  for (int d=0;d<32;d++) o[(size_t)q*256 + h*32 + d] = acc[d]*inv;
}

// ---------------------------------------------------------------- launch
extern "C" void kernel_launch(void* const* d_in, const int* in_sizes, int n_in,
                              void* d_out, int out_size, void* d_ws, size_t ws_size,
                              hipStream_t stream)
{
  (void)in_sizes; (void)n_in; (void)out_size; (void)ws_size;
  const float* xc   = (const float*)d_in[0];
  const float* yc   = (const float*)d_in[1];
  const float* xt   = (const float*)d_in[2];
  const float* eW1  = (const float*)d_in[3];
  const float* eb1  = (const float*)d_in[4];
  const float* eW2  = (const float*)d_in[5];
  const float* eb2  = (const float*)d_in[6];
  const float* Wqkv = (const float*)d_in[7];
  const float* bqkv = (const float*)d_in[8];
  const float* Wo   = (const float*)d_in[9];
  const float* bo   = (const float*)d_in[10];
  const float* ln1g = (const float*)d_in[11];
  const float* ln1b = (const float*)d_in[12];
  const float* ln2g = (const float*)d_in[13];
  const float* ln2b = (const float*)d_in[14];
  const float* Wff1 = (const float*)d_in[15];
  const float* bff1 = (const float*)d_in[16];
  const float* Wff2 = (const float*)d_in[17];
  const float* bff2 = (const float*)d_in[18];

  // OUTPUT IS FLOAT32 (proven round 9): d_out = [8][1024][256] f32 = 8 MB.
  // Use it directly as the residual stream; every element written by encoder.
  float* zf = (float*)d_out;

  // workspace scratch (per-batch, 9 MB)
  char* ws = (char*)d_ws;
  float* hb    = (float*)(ws);                          // [1024][256]  1 MB
  float* qkvb  = (float*)(ws + (size_t) 1*1024*1024);   // [1024][768]  3 MB
  float* attnb = (float*)(ws + (size_t) 4*1024*1024);   // [1024][256]  1 MB
  float* ffhb  = (float*)(ws + (size_t) 5*1024*1024);   // [1024][1024] 4 MB

  encoder_kernel<<<8192, 256, 0, stream>>>(xc, yc, xt, eW1, eb1, eW2, eb2, zf);

  for (int b=0; b<8; b++){
    float* zb = zf + (size_t)b*1024*256;
    for (int l=0; l<6; l++){
      ln_naive<<<16, 64, 0, stream>>>(zb, ln1g + l*256, ln1b + l*256, hb, 1024);
      gemm_naive<<<3072, 256, 0, stream>>>(hb, Wqkv + (size_t)l*256*768, bqkv + l*768,
                                           nullptr, qkvb, 0, 1024, 768, 256);
      attn_naive<<<128, 64, 0, stream>>>(qkvb, attnb);
      gemm_naive<<<1024, 256, 0, stream>>>(attnb, Wo + (size_t)l*256*256, bo + l*256,
                                           zb, zb, 0, 1024, 256, 256);
      ln_naive<<<16, 64, 0, stream>>>(zb, ln2g + l*256, ln2b + l*256, hb, 1024);
      gemm_naive<<<4096, 256, 0, stream>>>(hb, Wff1 + (size_t)l*256*1024, bff1 + l*1024,
                                           nullptr, ffhb, 1, 1024, 1024, 256);
      gemm_naive<<<1024, 256, 0, stream>>>(ffhb, Wff2 + (size_t)l*1024*256, bff2 + l*256,
                                           zb, zb, 0, 1024, 256, 1024);
    }
  }
}

// Round 11
// 11657.059 us; speedup vs baseline: 3.6386x; 3.6386x over previous
//
#include <hip/hip_runtime.h>

// ---------------------------------------------------------------- encoder
// One block per token (all 8 batches); z = d_out residual stream, f32.
__global__ __launch_bounds__(256) void encoder_kernel(
    const float* __restrict__ xc, const float* __restrict__ yc, const float* __restrict__ xt,
    const float* __restrict__ W1, const float* __restrict__ b1,
    const float* __restrict__ W2, const float* __restrict__ b2,
    float* __restrict__ z)
{
  __shared__ float zin[10];
  __shared__ float hid[256];
  int blk = blockIdx.x; int b = blk>>10; int t = blk & 1023;
  int tid = threadIdx.x;
  if (tid < 10){
    float v;
    if (tid < 8)      v = (t<512) ? xc[((size_t)b*512+t)*8+tid] : xt[((size_t)b*512+(t-512))*8+tid];
    else if (tid==8)  v = (t<512) ? yc[(size_t)b*512+t] : 0.f;
    else              v = (t<512) ? 0.f : 1.f;
    zin[tid]=v;
  }
  __syncthreads();
  float s = b1[tid];
  #pragma unroll
  for (int i=0;i<10;i++) s += zin[i]*W1[i*256+tid];
  hid[tid] = fmaxf(s, 0.f);
  __syncthreads();
  float o = b2[tid];
  for (int j=0;j<256;j++) o += hid[j]*W2[j*256+tid];
  z[((size_t)b*1024+t)*256 + tid] = o;
}

// ---------------------------------------------------------------- layernorm
// One block per row, LDS tree reduction. f32 in/out.
__global__ __launch_bounds__(256) void ln_fast(const float* __restrict__ z,
    const float* __restrict__ g, const float* __restrict__ be, float* __restrict__ h)
{
  __shared__ float red[256];
  int row = blockIdx.x, tid = threadIdx.x;
  float x = z[(size_t)row*256 + tid];
  red[tid] = x; __syncthreads();
  for (int s=128; s>0; s>>=1){ if (tid<s) red[tid]+=red[tid+s]; __syncthreads(); }
  float mu = red[0] * (1.f/256.f); __syncthreads();
  float d = x - mu;
  red[tid] = d*d; __syncthreads();
  for (int s=128; s>0; s>>=1){ if (tid<s) red[tid]+=red[tid+s]; __syncthreads(); }
  float var = red[0] * (1.f/256.f);
  float r = rsqrtf(var + 1e-5f);
  h[(size_t)row*256+tid] = d*r*g[tid] + be[tid];
}

// ---------------------------------------------------------------- tiled f32 GEMM
// out[M x N] = EPI(A[M x K] @ B[K x N] + bias)    (B row-major as stored)
// EPI 0: plain ; 1: relu ; 2: + resid (out may alias resid; per-thread RMW)
// 64x64 tile / block, 4x4 micro-tile / thread, K-slice 16.
template<int EPI>
__global__ __launch_bounds__(256) void gemm_f32(
    const float* __restrict__ A, const float* __restrict__ B,
    const float* __restrict__ bias, const float* __restrict__ resid,
    float* __restrict__ out, int N, int K)
{
  __shared__ float As[16][68];   // [k][m], +4 pad: 2-way max on write, clean reads
  __shared__ float Bs[16][68];   // [k][n]
  const int tid = threadIdx.x;
  const int tx = tid & 15, ty = tid >> 4;        // micro-tile: rows ty*4+i, cols tx*4+j
  const int m0 = blockIdx.y*64, n0 = blockIdx.x*64;
  const int am = tid >> 2, ak = (tid & 3) * 4;   // A staging: row am, k-offset ak
  const int bk = tid >> 4, bn = (tid & 15) * 4;  // B staging: k-row bk, col bn
  float acc[4][4] = {};
  for (int kk = 0; kk < K; kk += 16){
    float4 av = *(const float4*)&A[(size_t)(m0+am)*K + kk + ak];
    float4 bv = *(const float4*)&B[(size_t)(kk+bk)*N + n0 + bn];
    __syncthreads();
    As[ak+0][am]=av.x; As[ak+1][am]=av.y; As[ak+2][am]=av.z; As[ak+3][am]=av.w;
    *(float4*)&Bs[bk][bn] = bv;
    __syncthreads();
    #pragma unroll
    for (int k=0;k<16;k++){
      float4 a = *(const float4*)&As[k][ty*4];
      float4 b = *(const float4*)&Bs[k][tx*4];
      float ar[4] = {a.x,a.y,a.z,a.w};
      float br[4] = {b.x,b.y,b.z,b.w};
      #pragma unroll
      for (int i=0;i<4;i++)
        #pragma unroll
        for (int j=0;j<4;j++)
          acc[i][j] += ar[i]*br[j];
    }
  }
  const int gc0 = n0 + tx*4;
  float4 bsv = *(const float4*)&bias[gc0];
  float bb[4] = {bsv.x,bsv.y,bsv.z,bsv.w};
  #pragma unroll
  for (int i=0;i<4;i++){
    int gr = m0 + ty*4 + i;
    size_t off = (size_t)gr*N + gc0;
    float4 o;
    float v0=acc[i][0]+bb[0], v1=acc[i][1]+bb[1], v2=acc[i][2]+bb[2], v3=acc[i][3]+bb[3];
    if (EPI==1){ v0=fmaxf(v0,0.f); v1=fmaxf(v1,0.f); v2=fmaxf(v2,0.f); v3=fmaxf(v3,0.f); }
    if (EPI==2){ float4 rv = *(const float4*)&resid[off]; v0+=rv.x; v1+=rv.y; v2+=rv.z; v3+=rv.w; }
    o.x=v0; o.y=v1; o.z=v2; o.w=v3;
    *(float4*)&out[off] = o;
  }
}

// ---------------------------------------------------------------- attention
// Two blocks-worth of batches per call: qkv [2][1024][768] f32 (q|k|v, 8hx32).
// Keys 0..511 for all rows; target rows (q>=512) also self-attend.
// Two-pass softmax; per-thread q; K/V rows are wave-broadcast L1 hits.
__global__ __launch_bounds__(128) void attn_f32(
    const float* __restrict__ qkv, float* __restrict__ o)
{
  const int tid = threadIdx.x;
  const int qc = blockIdx.x, h = blockIdx.y, bb = blockIdx.z;
  const float* base = qkv + (size_t)bb*1024*768;
  const int q = qc*128 + tid;
  const float sc = 0.17677669529663687f;   // 1/sqrt(32)
  float Q[32];
  {
    const float4* qp = (const float4*)&base[(size_t)q*768 + h*32];
    #pragma unroll
    for (int p=0;p<8;p++){
      float4 t = qp[p];
      Q[p*4+0]=t.x*sc; Q[p*4+1]=t.y*sc; Q[p*4+2]=t.z*sc; Q[p*4+3]=t.w*sc;
    }
  }
  const int nk = (q >= 512) ? 513 : 512;
  float mx = -1e30f;
  for (int j=0;j<nk;j++){
    int kr = (j<512) ? j : q;
    const float4* kp = (const float4*)&base[(size_t)kr*768 + 256 + h*32];
    float dot = 0.f;
    #pragma unroll
    for (int p=0;p<8;p++){
      float4 t = kp[p];
      dot += Q[p*4+0]*t.x + Q[p*4+1]*t.y + Q[p*4+2]*t.z + Q[p*4+3]*t.w;
    }
    mx = fmaxf(mx, dot);
  }
  float acc[32];
  #pragma unroll
  for (int d=0;d<32;d++) acc[d]=0.f;
  float lsum = 0.f;
  for (int j=0;j<nk;j++){
    int kr = (j<512) ? j : q;
    const float4* kp = (const float4*)&base[(size_t)kr*768 + 256 + h*32];
    float dot = 0.f;
    #pragma unroll
    for (int p=0;p<8;p++){
      float4 t = kp[p];
      dot += Q[p*4+0]*t.x + Q[p*4+1]*t.y + Q[p*4+2]*t.z + Q[p*4+3]*t.w;
    }
    float p = __expf(dot - mx);
    lsum += p;
    const float4* vp = (const float4*)&base[(size_t)kr*768 + 512 + h*32];
    #pragma unroll
    for (int pp=0;pp<8;pp++){
      float4 t = vp[pp];
      acc[pp*4+0] += p*t.x; acc[pp*4+1] += p*t.y;
      acc[pp*4+2] += p*t.z; acc[pp*4+3] += p*t.w;
    }
  }
  float inv = 1.f/lsum;
  float* op = o + ((size_t)bb*1024 + q)*256 + h*32;
  #pragma unroll
  for (int p=0;p<8;p++){
    float4 t;
    t.x=acc[p*4+0]*inv; t.y=acc[p*4+1]*inv; t.z=acc[p*4+2]*inv; t.w=acc[p*4+3]*inv;
    *(float4*)&op[p*4] = t;
  }
}

// ---------------------------------------------------------------- launch
extern "C" void kernel_launch(void* const* d_in, const int* in_sizes, int n_in,
                              void* d_out, int out_size, void* d_ws, size_t ws_size,
                              hipStream_t stream)
{
  (void)in_sizes; (void)n_in; (void)out_size; (void)ws_size;
  const float* xc   = (const float*)d_in[0];
  const float* yc   = (const float*)d_in[1];
  const float* xt   = (const float*)d_in[2];
  const float* eW1  = (const float*)d_in[3];
  const float* eb1  = (const float*)d_in[4];
  const float* eW2  = (const float*)d_in[5];
  const float* eb2  = (const float*)d_in[6];
  const float* Wqkv = (const float*)d_in[7];
  const float* bqkv = (const float*)d_in[8];
  const float* Wo   = (const float*)d_in[9];
  const float* bo   = (const float*)d_in[10];
  const float* ln1g = (const float*)d_in[11];
  const float* ln1b = (const float*)d_in[12];
  const float* ln2g = (const float*)d_in[13];
  const float* ln2b = (const float*)d_in[14];
  const float* Wff1 = (const float*)d_in[15];
  const float* bff1 = (const float*)d_in[16];
  const float* Wff2 = (const float*)d_in[17];
  const float* bff2 = (const float*)d_in[18];

  // residual stream lives directly in d_out: [8][1024][256] f32 = 8 MB
  float* zf = (float*)d_out;

  // workspace (16 MB used; >=18 MB proven available round 8)
  char* ws = (char*)d_ws;
  float* hb      = (float*)(ws);                        // [8192][256] 8 MB  (LN out / attn out)
  float* scratch = (float*)(ws + (size_t)8*1024*1024);  // 8 MB: qkv chunk (6 MB) / ffh chunk (8 MB)

  encoder_kernel<<<8192, 256, 0, stream>>>(xc, yc, xt, eW1, eb1, eW2, eb2, zf);

  for (int l=0; l<6; l++){
    const float* Wq = Wqkv + (size_t)l*256*768;
    const float* Wl = Wo   + (size_t)l*256*256;
    const float* W1 = Wff1 + (size_t)l*256*1024;
    const float* W2 = Wff2 + (size_t)l*1024*256;

    // ---- attention sublayer ----
    ln_fast<<<8192, 256, 0, stream>>>(zf, ln1g+l*256, ln1b+l*256, hb);
    for (int c=0; c<4; c++){           // 2 batches per chunk
      float* hrows = hb + (size_t)c*2048*256;
      gemm_f32<0><<<dim3(12,32), 256, 0, stream>>>(hrows, Wq, bqkv+l*768,
                                                   nullptr, scratch, 768, 256);
      attn_f32<<<dim3(8,8,2), 128, 0, stream>>>(scratch, hrows);
    }
    gemm_f32<2><<<dim3(4,128), 256, 0, stream>>>(hb, Wl, bo+l*256, zf, zf, 256, 256);

    // ---- FF sublayer ----
    ln_fast<<<8192, 256, 0, stream>>>(zf, ln2g+l*256, ln2b+l*256, hb);
    for (int c=0; c<4; c++){
      float* hrows = hb + (size_t)c*2048*256;
      float* zrows = zf + (size_t)c*2048*256;
      gemm_f32<1><<<dim3(16,32), 256, 0, stream>>>(hrows, W1, bff1+l*1024,
                                                   nullptr, scratch, 1024, 256);
      gemm_f32<2><<<dim3(4,32), 256, 0, stream>>>(scratch, W2, bff2+l*256,
                                                  zrows, zrows, 256, 1024);
    }
  }
}

// Round 12
// 3477.149 us; speedup vs baseline: 12.1982x; 3.3525x over previous
//
#include <hip/hip_runtime.h>

// ---------------------------------------------------------------- encoder
__global__ __launch_bounds__(256) void encoder_kernel(
    const float* __restrict__ xc, const float* __restrict__ yc, const float* __restrict__ xt,
    const float* __restrict__ W1, const float* __restrict__ b1,
    const float* __restrict__ W2, const float* __restrict__ b2,
    float* __restrict__ z)
{
  __shared__ float zin[10];
  __shared__ float hid[256];
  int blk = blockIdx.x; int b = blk>>10; int t = blk & 1023;
  int tid = threadIdx.x;
  if (tid < 10){
    float v;
    if (tid < 8)      v = (t<512) ? xc[((size_t)b*512+t)*8+tid] : xt[((size_t)b*512+(t-512))*8+tid];
    else if (tid==8)  v = (t<512) ? yc[(size_t)b*512+t] : 0.f;
    else              v = (t<512) ? 0.f : 1.f;
    zin[tid]=v;
  }
  __syncthreads();
  float s = b1[tid];
  #pragma unroll
  for (int i=0;i<10;i++) s += zin[i]*W1[i*256+tid];
  hid[tid] = fmaxf(s, 0.f);
  __syncthreads();
  float o = b2[tid];
  for (int j=0;j<256;j++) o += hid[j]*W2[j*256+tid];
  z[((size_t)b*1024+t)*256 + tid] = o;
}

// ---------------------------------------------------------------- layernorm
__global__ __launch_bounds__(256) void ln_fast(const float* __restrict__ z,
    const float* __restrict__ g, const float* __restrict__ be, float* __restrict__ h)
{
  __shared__ float red[256];
  int row = blockIdx.x, tid = threadIdx.x;
  float x = z[(size_t)row*256 + tid];
  red[tid] = x; __syncthreads();
  for (int s=128; s>0; s>>=1){ if (tid<s) red[tid]+=red[tid+s]; __syncthreads(); }
  float mu = red[0] * (1.f/256.f); __syncthreads();
  float d = x - mu;
  red[tid] = d*d; __syncthreads();
  for (int s=128; s>0; s>>=1){ if (tid<s) red[tid]+=red[tid+s]; __syncthreads(); }
  float var = red[0] * (1.f/256.f);
  float r = rsqrtf(var + 1e-5f);
  h[(size_t)row*256+tid] = d*r*g[tid] + be[tid];
}

// ---------------------------------------------------------------- tiled f32 GEMM
// out[M x N] = EPI(A[M x K] @ B[K x N] + bias)
// EPI 0: plain ; 1: relu ; 2: + resid (out may alias resid)
// 64x64 tile / block, 4x4 micro-tile / thread, K-slice 16.
template<int EPI>
__global__ __launch_bounds__(256) void gemm_f32(
    const float* __restrict__ A, const float* __restrict__ B,
    const float* __restrict__ bias, const float* __restrict__ resid,
    float* __restrict__ out, int N, int K)
{
  __shared__ float As[16][68];
  __shared__ float Bs[16][68];
  const int tid = threadIdx.x;
  const int tx = tid & 15, ty = tid >> 4;
  const int m0 = blockIdx.y*64, n0 = blockIdx.x*64;
  const int am = tid >> 2, ak = (tid & 3) * 4;
  const int bk = tid >> 4, bn = (tid & 15) * 4;
  float acc[4][4] = {};
  for (int kk = 0; kk < K; kk += 16){
    float4 av = *(const float4*)&A[(size_t)(m0+am)*K + kk + ak];
    float4 bv = *(const float4*)&B[(size_t)(kk+bk)*N + n0 + bn];
    __syncthreads();
    As[ak+0][am]=av.x; As[ak+1][am]=av.y; As[ak+2][am]=av.z; As[ak+3][am]=av.w;
    *(float4*)&Bs[bk][bn] = bv;
    __syncthreads();
    #pragma unroll
    for (int k=0;k<16;k++){
      float4 a = *(const float4*)&As[k][ty*4];
      float4 b = *(const float4*)&Bs[k][tx*4];
      float ar[4] = {a.x,a.y,a.z,a.w};
      float br[4] = {b.x,b.y,b.z,b.w};
      #pragma unroll
      for (int i=0;i<4;i++)
        #pragma unroll
        for (int j=0;j<4;j++)
          acc[i][j] += ar[i]*br[j];
    }
  }
  const int gc0 = n0 + tx*4;
  float4 bsv = *(const float4*)&bias[gc0];
  float bb[4] = {bsv.x,bsv.y,bsv.z,bsv.w};
  #pragma unroll
  for (int i=0;i<4;i++){
    int gr = m0 + ty*4 + i;
    size_t off = (size_t)gr*N + gc0;
    float4 o;
    float v0=acc[i][0]+bb[0], v1=acc[i][1]+bb[1], v2=acc[i][2]+bb[2], v3=acc[i][3]+bb[3];
    if (EPI==1){ v0=fmaxf(v0,0.f); v1=fmaxf(v1,0.f); v2=fmaxf(v2,0.f); v3=fmaxf(v3,0.f); }
    if (EPI==2){ float4 rv = *(const float4*)&resid[off]; v0+=rv.x; v1+=rv.y; v2+=rv.z; v3+=rv.w; }
    o.x=v0; o.y=v1; o.z=v2; o.w=v3;
    *(float4*)&out[off] = o;
  }
}

// ---------------------------------------------------------------- attention v2
// Online-softmax single pass, j unrolled x4. qkv: [nb][1024][768] f32.
// Keys 0..511 for all rows; target rows (q>=512, i.e. qc>=4 -- block-uniform)
// also attend to themselves. Output written to o[(b*1024+q)*256 + h*32 ..].
__global__ __launch_bounds__(128) void attn_v2(
    const float* __restrict__ qkv, float* __restrict__ o)
{
  const int tid = threadIdx.x;
  const int qc = blockIdx.x, h = blockIdx.y, b = blockIdx.z;
  const float* base = qkv + (size_t)b*1024*768;
  const int q = qc*128 + tid;
  const float sc = 0.17677669529663687f;   // 1/sqrt(32)
  float Q[32];
  {
    const float4* qp = (const float4*)&base[(size_t)q*768 + h*32];
    #pragma unroll
    for (int p=0;p<8;p++){
      float4 t = qp[p];
      Q[p*4+0]=t.x*sc; Q[p*4+1]=t.y*sc; Q[p*4+2]=t.z*sc; Q[p*4+3]=t.w*sc;
    }
  }
  float m = -1e30f, l = 0.f;
  float acc[32];
  #pragma unroll
  for (int d=0;d<32;d++) acc[d]=0.f;

  for (int j=0; j<512; j+=4){
    float d0=0.f,d1=0.f,d2=0.f,d3=0.f;
    const float4* k0 = (const float4*)&base[(size_t)(j+0)*768 + 256 + h*32];
    const float4* k1 = (const float4*)&base[(size_t)(j+1)*768 + 256 + h*32];
    const float4* k2 = (const float4*)&base[(size_t)(j+2)*768 + 256 + h*32];
    const float4* k3 = (const float4*)&base[(size_t)(j+3)*768 + 256 + h*32];
    #pragma unroll
    for (int p=0;p<8;p++){
      float4 a=k0[p], c=k1[p], e=k2[p], f=k3[p];
      d0 += Q[p*4+0]*a.x + Q[p*4+1]*a.y + Q[p*4+2]*a.z + Q[p*4+3]*a.w;
      d1 += Q[p*4+0]*c.x + Q[p*4+1]*c.y + Q[p*4+2]*c.z + Q[p*4+3]*c.w;
      d2 += Q[p*4+0]*e.x + Q[p*4+1]*e.y + Q[p*4+2]*e.z + Q[p*4+3]*e.w;
      d3 += Q[p*4+0]*f.x + Q[p*4+1]*f.y + Q[p*4+2]*f.z + Q[p*4+3]*f.w;
    }
    float mn = fmaxf(fmaxf(fmaxf(d0,d1),fmaxf(d2,d3)), m);
    float corr = __expf(m - mn);
    float p0 = __expf(d0-mn), p1 = __expf(d1-mn), p2 = __expf(d2-mn), p3 = __expf(d3-mn);
    l = l*corr + (p0+p1+p2+p3);
    const float4* v0 = (const float4*)&base[(size_t)(j+0)*768 + 512 + h*32];
    const float4* v1 = (const float4*)&base[(size_t)(j+1)*768 + 512 + h*32];
    const float4* v2 = (const float4*)&base[(size_t)(j+2)*768 + 512 + h*32];
    const float4* v3 = (const float4*)&base[(size_t)(j+3)*768 + 512 + h*32];
    #pragma unroll
    for (int p=0;p<8;p++){
      float4 a=v0[p], c=v1[p], e=v2[p], f=v3[p];
      acc[p*4+0] = acc[p*4+0]*corr + p0*a.x + p1*c.x + p2*e.x + p3*f.x;
      acc[p*4+1] = acc[p*4+1]*corr + p0*a.y + p1*c.y + p2*e.y + p3*f.y;
      acc[p*4+2] = acc[p*4+2]*corr + p0*a.z + p1*c.z + p2*e.z + p3*f.z;
      acc[p*4+3] = acc[p*4+3]*corr + p0*a.w + p1*c.w + p2*e.w + p3*f.w;
    }
    m = mn;
  }
  if (qc >= 4){   // block-uniform: all q in this block are targets -> self-attend
    const float4* kp = (const float4*)&base[(size_t)q*768 + 256 + h*32];
    float d0 = 0.f;
    #pragma unroll
    for (int p=0;p<8;p++){
      float4 t = kp[p];
      d0 += Q[p*4+0]*t.x + Q[p*4+1]*t.y + Q[p*4+2]*t.z + Q[p*4+3]*t.w;
    }
    float mn = fmaxf(m, d0);
    float corr = __expf(m - mn);
    float p0 = __expf(d0 - mn);
    l = l*corr + p0;
    const float4* vp = (const float4*)&base[(size_t)q*768 + 512 + h*32];
    #pragma unroll
    for (int p=0;p<8;p++){
      float4 t = vp[p];
      acc[p*4+0] = acc[p*4+0]*corr + p0*t.x;
      acc[p*4+1] = acc[p*4+1]*corr + p0*t.y;
      acc[p*4+2] = acc[p*4+2]*corr + p0*t.z;
      acc[p*4+3] = acc[p*4+3]*corr + p0*t.w;
    }
  }
  float inv = 1.f/l;
  float* op = o + ((size_t)b*1024 + q)*256 + h*32;
  #pragma unroll
  for (int p=0;p<8;p++){
    float4 t;
    t.x=acc[p*4+0]*inv; t.y=acc[p*4+1]*inv; t.z=acc[p*4+2]*inv; t.w=acc[p*4+3]*inv;
    *(float4*)&op[p*4] = t;
  }
}

// ---------------------------------------------------------------- launch
extern "C" void kernel_launch(void* const* d_in, const int* in_sizes, int n_in,
                              void* d_out, int out_size, void* d_ws, size_t ws_size,
                              hipStream_t stream)
{
  (void)in_sizes; (void)n_in; (void)out_size;
  const float* xc   = (const float*)d_in[0];
  const float* yc   = (const float*)d_in[1];
  const float* xt   = (const float*)d_in[2];
  const float* eW1  = (const float*)d_in[3];
  const float* eb1  = (const float*)d_in[4];
  const float* eW2  = (const float*)d_in[5];
  const float* eb2  = (const float*)d_in[6];
  const float* Wqkv = (const float*)d_in[7];
  const float* bqkv = (const float*)d_in[8];
  const float* Wo   = (const float*)d_in[9];
  const float* bo   = (const float*)d_in[10];
  const float* ln1g = (const float*)d_in[11];
  const float* ln1b = (const float*)d_in[12];
  const float* ln2g = (const float*)d_in[13];
  const float* ln2b = (const float*)d_in[14];
  const float* Wff1 = (const float*)d_in[15];
  const float* bff1 = (const float*)d_in[16];
  const float* Wff2 = (const float*)d_in[17];
  const float* bff2 = (const float*)d_in[18];

  float* zf = (float*)d_out;            // residual stream [8][1024][256] f32 = 8 MB
  char* ws = (char*)d_ws;
  float* hb      = (float*)(ws);                        // 8 MB (LN out / attn out)
  float* scratch = (float*)(ws + (size_t)8*1024*1024);  // qkv / ffh

  const bool bigws = (ws_size == 0) || (ws_size >= (size_t)33*1024*1024);

  encoder_kernel<<<8192, 256, 0, stream>>>(xc, yc, xt, eW1, eb1, eW2, eb2, zf);

  for (int l=0; l<6; l++){
    const float* Wq = Wqkv + (size_t)l*256*768;
    const float* Wl = Wo   + (size_t)l*256*256;
    const float* W1 = Wff1 + (size_t)l*256*1024;
    const float* W2 = Wff2 + (size_t)l*1024*256;

    ln_fast<<<8192, 256, 0, stream>>>(zf, ln1g+l*256, ln1b+l*256, hb);
    if (bigws){
      // full-batch: qkv = 24 MB scratch
      gemm_f32<0><<<dim3(12,128), 256, 0, stream>>>(hb, Wq, bqkv+l*768,
                                                    nullptr, scratch, 768, 256);
      attn_v2<<<dim3(8,8,8), 128, 0, stream>>>(scratch, hb);   // hb consumed by gemm above
    } else {
      for (int c=0; c<4; c++){           // 2 batches per chunk (6 MB scratch)
        float* hrows = hb + (size_t)c*2048*256;
        gemm_f32<0><<<dim3(12,32), 256, 0, stream>>>(hrows, Wq, bqkv+l*768,
                                                     nullptr, scratch, 768, 256);
        attn_v2<<<dim3(8,8,2), 128, 0, stream>>>(scratch, hrows);
      }
    }
    gemm_f32<2><<<dim3(4,128), 256, 0, stream>>>(hb, Wl, bo+l*256, zf, zf, 256, 256);

    ln_fast<<<8192, 256, 0, stream>>>(zf, ln2g+l*256, ln2b+l*256, hb);
    if (bigws){
      for (int c=0; c<2; c++){           // 4-batch FF chunks (ffh 16 MB scratch)
        float* hrows = hb + (size_t)c*4096*256;
        float* zrows = zf + (size_t)c*4096*256;
        gemm_f32<1><<<dim3(16,64), 256, 0, stream>>>(hrows, W1, bff1+l*1024,
                                                     nullptr, scratch, 1024, 256);
        gemm_f32<2><<<dim3(4,64), 256, 0, stream>>>(scratch, W2, bff2+l*256,
                                                    zrows, zrows, 256, 1024);
      }
    } else {
      for (int c=0; c<4; c++){           // 2-batch FF chunks (ffh 8 MB scratch)
        float* hrows = hb + (size_t)c*2048*256;
        float* zrows = zf + (size_t)c*2048*256;
        gemm_f32<1><<<dim3(16,32), 256, 0, stream>>>(hrows, W1, bff1+l*1024,
                                                     nullptr, scratch, 1024, 256);
        gemm_f32<2><<<dim3(4,32), 256, 0, stream>>>(scratch, W2, bff2+l*256,
                                                    zrows, zrows, 256, 1024);
      }
    }
  }
}